// Round 3
// baseline (58726.331 us; speedup 1.0000x reference)
//
#include <hip/hip_runtime.h>
#include <math.h>

#define H    256
#define BB   64
#define LL   128
#define LBL  128
#define NSTEP (BB*LL)      // 8192 sequential cell steps
#define GDIM (4*H)         // 1024 gate rows
#define KDIM (4*H)         // 1024 feats dim
#define W5   (5*H)         // 1280 (W_ih leading dim)
#define NROW (NSTEP + 64)  // tagged-h rows: row r holds h_{r-64}, tag salt+r
#define NHELP 64           // helper WGs computing z = pre + Wo*h_{k-64}
#define ZRING 64           // z ring depth (helpers provably <=64 steps ahead)

typedef unsigned long long ull;
typedef unsigned int u32;
typedef _Float16 h2v __attribute__((ext_vector_type(2)));

#if defined(__has_builtin)
#  if __has_builtin(__builtin_amdgcn_fdot2)
#    define HAVE_FDOT2 1
#  endif
#endif

// v_dot2_f32_f16: 2 fp16 MACs, fp32 accumulate. Fallback: cvt+fma (correct, slower).
__device__ __forceinline__ float dot2f(u32 a, u32 b, float c)
{
    union { u32 u; h2v h; } ua, ub; ua.u = a; ub.u = b;
#ifdef HAVE_FDOT2
    return __builtin_amdgcn_fdot2(ua.h, ub.h, c, false);
#else
    return c + (float)ua.h[0]*(float)ub.h[0] + (float)ua.h[1]*(float)ub.h[1];
#endif
}

// tanh via one exp: safe for all x (argument to exp is always <= 0)
__device__ __forceinline__ float tanh_fast(float x)
{
    const float ax = fabsf(x);
    const float t  = __expf(-2.f*ax);
    const float r  = (1.f - t)/(1.f + t);
    return x >= 0.f ? r : -r;
}

__device__ __forceinline__ float sigm_fast(float x)
{
    return 1.f/(1.f + __expf(-x));
}

// ---------------------------------------------------------------------------
// REPLAY-SAFE TAG PROTOCOL (see round-1 post-mortem): every tag = salt + k,
// salt = (++RUN)*65536 persisted in workspace. Stale tags from a previous
// replay can never match the current run -> helpers cannot run ahead and
// overwrite unconsumed Z-ring slots. Verified passing (absmax 0.0039).
// ---------------------------------------------------------------------------

// K0: bump RUN, write tagged zero rows 0..63 of HT (h=0.0f, tag=salt+row).
__global__ __launch_bounds__(256) void k_init(ull* __restrict__ HT,
                                              ull* __restrict__ RUN)
{
    __shared__ u32 s_salt;
    const int tid = threadIdx.x;
    if (tid == 0) {
        ull r = __hip_atomic_load(RUN, __ATOMIC_RELAXED, __HIP_MEMORY_SCOPE_AGENT) + 1;
        __hip_atomic_store(RUN, r, __ATOMIC_RELAXED, __HIP_MEMORY_SCOPE_AGENT);
        s_salt = (u32)r * 65536u;
    }
    __syncthreads();
    const u32 salt = s_salt;
    for (int i = tid; i < 64 * H; i += 256) {
        const u32 r = (u32)(i >> 8);              // row 0..63
        HT[i] = ((ull)(salt + r) << 32);          // low 32 = 0.0f bits
    }
}

// ---------------------------------------------------------------------------
// K1: PRE[k][row] = bias[row] + sum_j W_ih[row][j] * feats[k][j], j<1024
//     (unchanged; ~2% of runtime)
// ---------------------------------------------------------------------------
__global__ __launch_bounds__(256) void k_pre(const float* __restrict__ x,
                                             const float* __restrict__ hi,
                                             const float* __restrict__ Wih,
                                             const float* __restrict__ bih,
                                             const float* __restrict__ bhh,
                                             _Float16* __restrict__ PREh)
{
    const int nb = blockIdx.x;   // row-block: rows nb*64 .. +63
    const int t  = blockIdx.y;   // time index == M-block (m_local = b)
    const int tid = threadIdx.x;
    const int tm = tid >> 4, tn = tid & 15;

    __shared__ float As[16][68];   // [kk][m_local], padded
    __shared__ float Bs[16][68];   // [kk][n_local]

    const int lm  = tid >> 2;          // 0..63
    const int lk4 = (tid & 3) * 4;     // 0,4,8,12

    float acc[4][4];
#pragma unroll
    for (int i = 0; i < 4; i++)
#pragma unroll
        for (int j = 0; j < 4; j++) acc[i][j] = 0.f;

    for (int j0 = 0; j0 < KDIM; j0 += 16) {
        const int j = j0 + lk4;
        float4 av;
        if (j < 512) av = *(const float4*)(x  + ((size_t)lm * LL + t) * 512 + j);
        else         av = *(const float4*)(hi + ((size_t)lm * LL + t) * 512 + (j - 512));
        float4 bv = *(const float4*)(Wih + (size_t)(nb * 64 + lm) * W5 + j);

        __syncthreads();   // protect LDS from previous iteration's readers
        As[lk4 + 0][lm] = av.x; As[lk4 + 1][lm] = av.y;
        As[lk4 + 2][lm] = av.z; As[lk4 + 3][lm] = av.w;
        Bs[lk4 + 0][lm] = bv.x; Bs[lk4 + 1][lm] = bv.y;
        Bs[lk4 + 2][lm] = bv.z; Bs[lk4 + 3][lm] = bv.w;
        __syncthreads();

#pragma unroll
        for (int kk = 0; kk < 16; kk++) {
            float4 a = *(const float4*)&As[kk][tm << 2];
            float4 b = *(const float4*)&Bs[kk][tn << 2];
            acc[0][0] += a.x * b.x; acc[0][1] += a.x * b.y; acc[0][2] += a.x * b.z; acc[0][3] += a.x * b.w;
            acc[1][0] += a.y * b.x; acc[1][1] += a.y * b.y; acc[1][2] += a.y * b.z; acc[1][3] += a.y * b.w;
            acc[2][0] += a.z * b.x; acc[2][1] += a.z * b.y; acc[2][2] += a.z * b.z; acc[2][3] += a.z * b.w;
            acc[3][0] += a.w * b.x; acc[3][1] += a.w * b.y; acc[3][2] += a.w * b.z; acc[3][3] += a.w * b.w;
        }
    }

    const int n0 = nb * 64 + tn * 4;
    float4 b1 = *(const float4*)(bih + n0);
    float4 b2 = *(const float4*)(bhh + n0);
    const float bx = b1.x + b2.x, by = b1.y + b2.y, bz = b1.z + b2.z, bw = b1.w + b2.w;
#pragma unroll
    for (int i = 0; i < 4; i++) {
        const size_t m = (size_t)t * 64 + tm * 4 + i;    // k index
        union { _Float16 h[4]; ull u; } p;
        p.h[0] = (_Float16)(acc[i][0] + bx);
        p.h[1] = (_Float16)(acc[i][1] + by);
        p.h[2] = (_Float16)(acc[i][2] + bz);
        p.h[3] = (_Float16)(acc[i][3] + bw);
        *(ull*)(PREh + m * GDIM + n0) = p.u;
    }
}

// ---------------------------------------------------------------------------
// K2: sequential recurrence, MASTER + HELPER architecture (salted tags).
//
//  ROUND-2 POST-MORTEM: __launch_bounds__(512) alone let the compiler cap
//  VGPRs at 128 -> the 192-reg wr[4][48] weight array spilled to scratch ->
//  ~3GB of serialized L2 scratch reloads on the critical path (57ms, VGPR
//  counter = 128 was the tell). FIX: __launch_bounds__(512, 2) = 2 waves/EU
//  = exactly 1 block/CU -> VGPR cap 256/wave (8 waves x 256 = full 2048-reg
//  CU pool). Live set ~232 regs -> weights stay register-resident.
//
//  MASTER (blockIdx 0, 512 threads, one CU): owns the whole critical chain.
//    h_{k-1} broadcast = LDS ping-pong + ONE __syncthreads per step.
//    Whh fp16: 192 packed dwords/thread in VGPRs (384KB) + 128KB LDS tail.
//    v_dot2_f32_f16, fp32 accumulate. Thread pair (2e,2e+1) = element e;
//    lane h covers K-half [128h,128h+128); 4 gate rows each; shfl_xor(1)
//    combines. Floor ~1024 VALU-issue cy/step, LDS reads overlapped.
//  HELPERS (blockIdx 1..64): z_k = pre_k + Wo*h_{k-64}, 64 steps of slack,
//    delivered via salted tagged-8B ring. All polls budget-bounded.
// ---------------------------------------------------------------------------
__device__ __forceinline__ float z_wait(ull v, const ull* p, u32 want, long long& budget)
{
    while ((u32)(v >> 32) != want) {
        if (--budget < 0) break;            // bounded exit on protocol failure
        v = __hip_atomic_load(p, __ATOMIC_RELAXED, __HIP_MEMORY_SCOPE_AGENT);
    }
    union { unsigned u; float f; } c; c.u = (unsigned)v;
    return c.f;
}

__device__ __forceinline__ float poll_sleep(const ull* p, u32 want, long long& budget)
{
    ull v = __hip_atomic_load(p, __ATOMIC_RELAXED, __HIP_MEMORY_SCOPE_AGENT);
    while ((u32)(v >> 32) != want) {
        if (--budget < 0) break;
        __builtin_amdgcn_s_sleep(16);       // helpers have ~32us slack/step
        v = __hip_atomic_load(p, __ATOMIC_RELAXED, __HIP_MEMORY_SCOPE_AGENT);
    }
    union { unsigned u; float f; } c; c.u = (unsigned)v;
    return c.f;
}

__global__ __launch_bounds__(512, 2) void k_rec(const _Float16* __restrict__ PREh,
                                                const float* __restrict__ Wih,
                                                const float* __restrict__ Whh,
                                                ull* __restrict__ HT,
                                                ull* __restrict__ Z,
                                                const ull* __restrict__ RUN)
{
    // 128KB weight tail, [plane = d4*2+h][row = g*256+e] -> lane-consecutive
    // 16B reads.
    __shared__ uint4 wlds[8192];
    __shared__ __align__(16) _Float16 hs[2][256];   // h ping-pong (fp16 pairs)
    __shared__ __align__(16) float hb[256];         // helper h_{k-64} stage

    const int tid = threadIdx.x;
    const u32 salt = (u32)__hip_atomic_load(RUN, __ATOMIC_RELAXED,
                                            __HIP_MEMORY_SCOPE_AGENT) * 65536u;

    if (blockIdx.x == 0) {
        // ================= MASTER =================
        const int e = tid >> 1;       // element 0..255
        const int h = tid & 1;        // K-half: cols [128h, 128h+128)

        // ---- stage weights: regs = cols [128h, 128h+96) as 48 packed dwords
        u32 wr[4][48];
#pragma unroll
        for (int g = 0; g < 4; ++g) {
            const float* W = Whh + (size_t)(g*256 + e)*H + h*128;
#pragma unroll
            for (int c = 0; c < 48; ++c) {
                float2 f = *(const float2*)(W + 2*c);
                union { h2v hh; u32 u; } p;
                p.hh[0] = (_Float16)f.x; p.hh[1] = (_Float16)f.y;
                wr[g][c] = p.u;
            }
        }
        // ---- LDS weights: cols [128h+96, 128h+128), 4 chunks of 4 dwords
#pragma unroll
        for (int g = 0; g < 4; ++g) {
            const float* W = Whh + (size_t)(g*256 + e)*H + h*128 + 96;
#pragma unroll
            for (int d4 = 0; d4 < 4; ++d4) {
                u32 u0, u1, u2, u3;
                {
                    float2 f; union { h2v hh; u32 uu; } p;
                    f = *(const float2*)(W + 8*d4 + 0); p.hh[0]=(_Float16)f.x; p.hh[1]=(_Float16)f.y; u0 = p.uu;
                    f = *(const float2*)(W + 8*d4 + 2); p.hh[0]=(_Float16)f.x; p.hh[1]=(_Float16)f.y; u1 = p.uu;
                    f = *(const float2*)(W + 8*d4 + 4); p.hh[0]=(_Float16)f.x; p.hh[1]=(_Float16)f.y; u2 = p.uu;
                    f = *(const float2*)(W + 8*d4 + 6); p.hh[0]=(_Float16)f.x; p.hh[1]=(_Float16)f.y; u3 = p.uu;
                }
                wlds[(d4*2 + h)*1024 + g*256 + e] = make_uint4(u0, u1, u2, u3);
            }
        }
        if (tid < 128) ((u32*)hs[0])[tid] = 0u;    // h_{-1} = 0

        // z addresses: lane h owns gates {2h, 2h+1}
        const ull* zp0 = Z + (size_t)(2*h    )*256 + e;
        const ull* zp1 = Z + (size_t)(2*h + 1)*256 + e;
        ull zc0 = __hip_atomic_load(zp0, __ATOMIC_RELAXED, __HIP_MEMORY_SCOPE_AGENT);
        ull zc1 = __hip_atomic_load(zp1, __ATOMIC_RELAXED, __HIP_MEMORY_SCOPE_AGENT);

        float c_state = 0.f;
        long long budget = 2000000LL;
        __syncthreads();

        for (int k = 0; k < NSTEP; ++k) {
            // ---- prefetch z for k+1 (issued now, validated next iteration)
            const size_t sl_n = (size_t)((k+1) & (ZRING-1)) * GDIM;
            ull zn0 = __hip_atomic_load(zp0 + sl_n, __ATOMIC_RELAXED, __HIP_MEMORY_SCOPE_AGENT);
            ull zn1 = __hip_atomic_load(zp1 + sl_n, __ATOMIC_RELAXED, __HIP_MEMORY_SCOPE_AGENT);

            // ---- dot phase: 256 dot2/thread (broadcast LDS h reads)
            const uint4* hp = (const uint4*)((const char*)hs[k & 1] + h*256);
            float acc[4] = {0.f, 0.f, 0.f, 0.f};
#pragma unroll
            for (int q = 0; q < 12; ++q) {
                uint4 hv = hp[q];
#pragma unroll
                for (int g = 0; g < 4; ++g) {
                    acc[g] = dot2f(wr[g][4*q+0], hv.x, acc[g]);
                    acc[g] = dot2f(wr[g][4*q+1], hv.y, acc[g]);
                    acc[g] = dot2f(wr[g][4*q+2], hv.z, acc[g]);
                    acc[g] = dot2f(wr[g][4*q+3], hv.w, acc[g]);
                }
            }
#pragma unroll
            for (int q = 12; q < 16; ++q) {
                uint4 hv = hp[q];
                const int pl = (q - 12)*2 + h;
#pragma unroll
                for (int g = 0; g < 4; ++g) {
                    uint4 wv = wlds[pl*1024 + g*256 + e];
                    acc[g] = dot2f(wv.x, hv.x, acc[g]);
                    acc[g] = dot2f(wv.y, hv.y, acc[g]);
                    acc[g] = dot2f(wv.z, hv.z, acc[g]);
                    acc[g] = dot2f(wv.w, hv.w, acc[g]);
                }
            }

            // ---- fold z (static indices only)
            const size_t sl = (size_t)(k & (ZRING-1)) * GDIM;
            const u32 want = salt + (u32)k;
            const float z0 = z_wait(zc0, zp0 + sl, want, budget);
            const float z1 = z_wait(zc1, zp1 + sl, want, budget);
            if (h == 0) { acc[0] += z0; acc[1] += z1; }
            else        { acc[2] += z0; acc[3] += z1; }

            // ---- combine K-halves (pair lanes 2e,2e+1); identical in both lanes
            const float s0 = acc[0] + __shfl_xor(acc[0], 1);
            const float s1 = acc[1] + __shfl_xor(acc[1], 1);
            const float s2 = acc[2] + __shfl_xor(acc[2], 1);
            const float s3 = acc[3] + __shfl_xor(acc[3], 1);

            const float iv = sigm_fast(s0);
            const float fv = sigm_fast(s1);
            const float gv = tanh_fast(s2);
            const float ov = sigm_fast(s3);
            c_state = fv * c_state + iv * gv;
            const float hn = ov * tanh_fast(c_state);

            // ---- publish: LDS ping-pong (next step) + global tagged row
            //      (helpers + k_fc). ONE barrier per step.
            if (h == 0) {
                hs[(k + 1) & 1][e] = (_Float16)hn;
                union { float f; unsigned u; } cv; cv.f = hn;
                __hip_atomic_store(&HT[(ull)(k + 64) * H + e],
                                   ((ull)(salt + (u32)(k + 64)) << 32) | cv.u,
                                   __ATOMIC_RELAXED, __HIP_MEMORY_SCOPE_AGENT);
            }
            zc0 = zn0; zc1 = zn1;
            __syncthreads();
        }
    } else {
        // ================= HELPERS =================
        // WG wg handles k = wg, wg+64, ... : z_k = pre_k + Wo * h_{k-64}
        const int wg = blockIdx.x - 1;          // 0..63  (== ring slot, always)
        long long budget = 200000LL;            // sleep-polls; worst hang ~0.1s
        const int r0 = tid, r1 = tid + 512;
        const float* w0 = Wih + (size_t)r0 * W5 + 4*H;   // Wo row r0 (L2-resident)
        const float* w1 = Wih + (size_t)r1 * W5 + 4*H;

        for (int k = wg; k < NSTEP; k += NHELP) {
            // stage h_{k-64}: HT row k, CURRENT-run tag salt+k (k<64: k_init)
            if (tid < H) {
                hb[tid] = poll_sleep(&HT[(ull)k * H + tid], salt + (u32)k, budget);
            }
            __syncthreads();

            float a0 = (float)PREh[(size_t)k * GDIM + r0];
            float a1 = (float)PREh[(size_t)k * GDIM + r1];
#pragma unroll 4
            for (int j = 0; j < H; j += 4) {
                float4 hv = *(const float4*)(hb + j);
                float4 wa = *(const float4*)(w0 + j);
                float4 wb = *(const float4*)(w1 + j);
                a0 += wa.x*hv.x + wa.y*hv.y + wa.z*hv.z + wa.w*hv.w;
                a1 += wb.x*hv.x + wb.y*hv.y + wb.z*hv.z + wb.w*hv.w;
            }
            union { float f; unsigned u; } c0, c1; c0.f = a0; c1.f = a1;
            const ull tg = (ull)(salt + (u32)k) << 32;
            __hip_atomic_store(&Z[(size_t)(k & (ZRING-1))*GDIM + r0], tg | c0.u,
                               __ATOMIC_RELAXED, __HIP_MEMORY_SCOPE_AGENT);
            __hip_atomic_store(&Z[(size_t)(k & (ZRING-1))*GDIM + r1], tg | c1.u,
                               __ATOMIC_RELAXED, __HIP_MEMORY_SCOPE_AGENT);
            __syncthreads();   // protect hb before next iteration's overwrite
        }
    }
}

// ---------------------------------------------------------------------------
// K3: out[b][t][l] = b_fc[l] + sum_j h_k[j] * W_fc[l][j],  k = t*64+b
//     (unchanged; ignores tags — runs after k_rec completes)
// ---------------------------------------------------------------------------
__global__ __launch_bounds__(256) void k_fc(const ull* __restrict__ HT,
                                            const float* __restrict__ Wfc,
                                            const float* __restrict__ bfc,
                                            float* __restrict__ out)
{
    __shared__ float hl[8 * 256];
    __shared__ float wl[128 * 65];
    const int blk = blockIdx.x;     // 0..1023, k = blk*8 + kk
    const int tid = threadIdx.x;

#pragma unroll
    for (int kk = 0; kk < 8; kk++) {
        ull v = HT[((ull)(blk * 8 + kk + 64)) * H + tid];
        union { unsigned u; float f; } c; c.u = (unsigned)v;
        hl[kk * 256 + tid] = c.f;
    }

    const int l = tid & 127, grp = tid >> 7;
    float a0 = 0.f, a1 = 0.f, a2 = 0.f, a3 = 0.f;

    for (int c = 0; c < 4; c++) {
        __syncthreads();   // orders hl (c==0) and wl reuse (c>0)
        for (int m = 0; m < 32; m++) {
            const int idx = m * 256 + tid;
            const int lr = idx >> 6, jc = idx & 63;
            wl[lr * 65 + jc] = Wfc[(size_t)lr * H + c * 64 + jc];
        }
        __syncthreads();
#pragma unroll 4
        for (int jc = 0; jc < 64; jc++) {
            const float wv = wl[l * 65 + jc];
            const int hj = c * 64 + jc;
            a0 += hl[(grp * 4 + 0) * 256 + hj] * wv;
            a1 += hl[(grp * 4 + 1) * 256 + hj] * wv;
            a2 += hl[(grp * 4 + 2) * 256 + hj] * wv;
            a3 += hl[(grp * 4 + 3) * 256 + hj] * wv;
        }
    }

    const float bias = bfc[l];
    float accs[4] = {a0, a1, a2, a3};
#pragma unroll
    for (int r = 0; r < 4; r++) {
        const int k = blk * 8 + grp * 4 + r;
        const int t = k >> 6, b = k & 63;
        out[((size_t)b * LL + t) * LBL + l] = accs[r] + bias;
    }
}

// ---------------------------------------------------------------------------
extern "C" void kernel_launch(void* const* d_in, const int* in_sizes, int n_in,
                              void* d_out, int out_size, void* d_ws, size_t ws_size,
                              hipStream_t stream)
{
    const float* x   = (const float*)d_in[0];
    const float* hi  = (const float*)d_in[1];
    const float* Wih = (const float*)d_in[2];
    const float* Whh = (const float*)d_in[3];
    const float* bih = (const float*)d_in[4];
    const float* bhh = (const float*)d_in[5];
    const float* Wfc = (const float*)d_in[6];
    const float* bfc = (const float*)d_in[7];
    float* out = (float*)d_out;

    const size_t preh_b = (size_t)NSTEP * GDIM * sizeof(_Float16);   // 16 MB
    const size_t ht_b   = (size_t)NROW * H * sizeof(ull);            // 16.9 MB
    const size_t z_b    = (size_t)ZRING * GDIM * sizeof(ull);        // 512 KB

    _Float16* PREh = (_Float16*)d_ws;
    ull*      HT   = (ull*)((char*)d_ws + preh_b);
    ull*      Zr   = (ull*)((char*)d_ws + preh_b + ht_b);
    ull*      RUN  = (ull*)((char*)d_ws + preh_b + ht_b + z_b);

    const size_t need = preh_b + ht_b + z_b + sizeof(ull);
    if (ws_size < need) return;   // visible failure instead of OOB writes

    k_init<<<1, 256, 0, stream>>>(HT, RUN);
    k_pre<<<dim3(GDIM / 64, LL), 256, 0, stream>>>(x, hi, Wih, bih, bhh, PREh);
    k_rec<<<1 + NHELP, 512, 0, stream>>>(PREh, Wih, Whh, HT, Zr, RUN);
    k_fc<<<NSTEP / 8, 256, 0, stream>>>(HT, Wfc, bfc, out);
}

// Round 5
// 56283.636 us; speedup vs baseline: 1.0434x; 1.0434x over previous
//
#include <hip/hip_runtime.h>
#include <math.h>

#define H    256
#define BB   64
#define LL   128
#define LBL  128
#define NSTEP (BB*LL)      // 8192 sequential cell steps
#define GDIM (4*H)         // 1024 gate rows
#define KDIM (4*H)         // 1024 feats dim
#define W5   (5*H)         // 1280 (W_ih leading dim)
#define NROW (NSTEP + 64)  // tagged-h rows: row r holds h_{r-64}, tag salt+r
#define NHELP 64           // helper WGs computing z = pre + Wo*h_{k-64}
#define ZRING 64           // z ring depth (helpers provably <=64 steps ahead)

typedef unsigned long long ull;
typedef unsigned int u32;
typedef _Float16 h2v __attribute__((ext_vector_type(2)));
typedef u32 u32x16 __attribute__((ext_vector_type(16)));

#if defined(__has_builtin)
#  if __has_builtin(__builtin_amdgcn_fdot2)
#    define HAVE_FDOT2 1
#  endif
#endif

// v_dot2_f32_f16: 2 fp16 MACs, fp32 accumulate. Fallback: cvt+fma (correct, slower).
__device__ __forceinline__ float dot2f(u32 a, u32 b, float c)
{
    union { u32 u; h2v h; } ua, ub; ua.u = a; ub.u = b;
#ifdef HAVE_FDOT2
    return __builtin_amdgcn_fdot2(ua.h, ub.h, c, false);
#else
    return c + (float)ua.h[0]*(float)ub.h[0] + (float)ua.h[1]*(float)ub.h[1];
#endif
}

// tanh via one exp: safe for all x (argument to exp is always <= 0)
__device__ __forceinline__ float tanh_fast(float x)
{
    const float ax = fabsf(x);
    const float t  = __expf(-2.f*ax);
    const float r  = (1.f - t)/(1.f + t);
    return x >= 0.f ? r : -r;
}

__device__ __forceinline__ float sigm_fast(float x)
{
    return 1.f/(1.f + __expf(-x));
}

// ---------------------------------------------------------------------------
// ROUND-4 POST-MORTEM / WEIGHT RESIDENCY:
// - u32 wr[4][48] (192 scalar elems, 768B) is SCRATCH-LOWERED by SROA
//   (aggregate too large to promote) -> launch_bounds hints can't help;
//   that was the 57ms scratch-reload wall (VGPR_Count pinned at 128 under
//   both (512) and (512,2) was the tell).
// - The AGPR inline-asm workaround MISCOMPILED (absmax 0.81 first run).
// Fix: 12 x ext_vector_type(16) variables = 192 dwords as first-class SSA
// vector values -> SROA keeps them; allocator gets ~240 live regs <= 256
// (the 2-waves/SIMD budget from __launch_bounds__(512,2)).
// ---------------------------------------------------------------------------
#define WVg(g,c) (wv[(g)*3 + ((c)>>4)][(c)&15])

// ---------------------------------------------------------------------------
// REPLAY-SAFE TAG PROTOCOL: every tag = salt + k, salt = (++RUN)*65536
// persisted in workspace. Stale tags from a previous replay never match the
// current run -> helpers cannot run ahead and overwrite unconsumed Z-ring
// slots. Verified passing twice (absmax 0.0039).
// ---------------------------------------------------------------------------

// K0: bump RUN, write tagged zero rows 0..63 of HT (h=0.0f, tag=salt+row).
__global__ __launch_bounds__(256) void k_init(ull* __restrict__ HT,
                                              ull* __restrict__ RUN)
{
    __shared__ u32 s_salt;
    const int tid = threadIdx.x;
    if (tid == 0) {
        ull r = __hip_atomic_load(RUN, __ATOMIC_RELAXED, __HIP_MEMORY_SCOPE_AGENT) + 1;
        __hip_atomic_store(RUN, r, __ATOMIC_RELAXED, __HIP_MEMORY_SCOPE_AGENT);
        s_salt = (u32)r * 65536u;
    }
    __syncthreads();
    const u32 salt = s_salt;
    for (int i = tid; i < 64 * H; i += 256) {
        const u32 r = (u32)(i >> 8);              // row 0..63
        HT[i] = ((ull)(salt + r) << 32);          // low 32 = 0.0f bits
    }
}

// ---------------------------------------------------------------------------
// K1: PRE[k][row] = bias[row] + sum_j W_ih[row][j] * feats[k][j], j<1024
//     (unchanged; ~2% of runtime)
// ---------------------------------------------------------------------------
__global__ __launch_bounds__(256) void k_pre(const float* __restrict__ x,
                                             const float* __restrict__ hi,
                                             const float* __restrict__ Wih,
                                             const float* __restrict__ bih,
                                             const float* __restrict__ bhh,
                                             _Float16* __restrict__ PREh)
{
    const int nb = blockIdx.x;   // row-block: rows nb*64 .. +63
    const int t  = blockIdx.y;   // time index == M-block (m_local = b)
    const int tid = threadIdx.x;
    const int tm = tid >> 4, tn = tid & 15;

    __shared__ float As[16][68];   // [kk][m_local], padded
    __shared__ float Bs[16][68];   // [kk][n_local]

    const int lm  = tid >> 2;          // 0..63
    const int lk4 = (tid & 3) * 4;     // 0,4,8,12

    float acc[4][4];
#pragma unroll
    for (int i = 0; i < 4; i++)
#pragma unroll
        for (int j = 0; j < 4; j++) acc[i][j] = 0.f;

    for (int j0 = 0; j0 < KDIM; j0 += 16) {
        const int j = j0 + lk4;
        float4 av;
        if (j < 512) av = *(const float4*)(x  + ((size_t)lm * LL + t) * 512 + j);
        else         av = *(const float4*)(hi + ((size_t)lm * LL + t) * 512 + (j - 512));
        float4 bv = *(const float4*)(Wih + (size_t)(nb * 64 + lm) * W5 + j);

        __syncthreads();   // protect LDS from previous iteration's readers
        As[lk4 + 0][lm] = av.x; As[lk4 + 1][lm] = av.y;
        As[lk4 + 2][lm] = av.z; As[lk4 + 3][lm] = av.w;
        Bs[lk4 + 0][lm] = bv.x; Bs[lk4 + 1][lm] = bv.y;
        Bs[lk4 + 2][lm] = bv.z; Bs[lk4 + 3][lm] = bv.w;
        __syncthreads();

#pragma unroll
        for (int kk = 0; kk < 16; kk++) {
            float4 a = *(const float4*)&As[kk][tm << 2];
            float4 b = *(const float4*)&Bs[kk][tn << 2];
            acc[0][0] += a.x * b.x; acc[0][1] += a.x * b.y; acc[0][2] += a.x * b.z; acc[0][3] += a.x * b.w;
            acc[1][0] += a.y * b.x; acc[1][1] += a.y * b.y; acc[1][2] += a.y * b.z; acc[1][3] += a.y * b.w;
            acc[2][0] += a.z * b.x; acc[2][1] += a.z * b.y; acc[2][2] += a.z * b.z; acc[2][3] += a.z * b.w;
            acc[3][0] += a.w * b.x; acc[3][1] += a.w * b.y; acc[3][2] += a.w * b.z; acc[3][3] += a.w * b.w;
        }
    }

    const int n0 = nb * 64 + tn * 4;
    float4 b1 = *(const float4*)(bih + n0);
    float4 b2 = *(const float4*)(bhh + n0);
    const float bx = b1.x + b2.x, by = b1.y + b2.y, bz = b1.z + b2.z, bw = b1.w + b2.w;
#pragma unroll
    for (int i = 0; i < 4; i++) {
        const size_t m = (size_t)t * 64 + tm * 4 + i;    // k index
        union { _Float16 h[4]; ull u; } p;
        p.h[0] = (_Float16)(acc[i][0] + bx);
        p.h[1] = (_Float16)(acc[i][1] + by);
        p.h[2] = (_Float16)(acc[i][2] + bz);
        p.h[3] = (_Float16)(acc[i][3] + bw);
        *(ull*)(PREh + m * GDIM + n0) = p.u;
    }
}

// ---------------------------------------------------------------------------
// K2: sequential recurrence, MASTER + HELPER architecture (salted tags).
//
//  MASTER (blockIdx 0, 512 threads, one CU): owns the whole critical chain.
//    h_{k-1} broadcast = LDS ping-pong + ONE __syncthreads per step.
//    Whh fp16 per thread-pair: cols [0,96) in 12 x u32x16 VGPR vectors
//    (192 regs), cols [96,128) in a swizzled 144KB LDS tail (pad every 8
//    elements -> <=2-way banks). v_dot2_f32_f16, fp32 accumulate. Thread
//    pair (2e,2e+1) = element e; lane h covers K-half [128h,128h+128);
//    4 gate rows each; shfl_xor(1) combines.
//  HELPERS (blockIdx 1..64): z_k = pre_k + Wo*h_{k-64}, 64 steps of slack,
//    delivered via salted tagged-8B ring. All polls budget-bounded.
// ---------------------------------------------------------------------------
__device__ __forceinline__ float z_wait(ull v, const ull* p, u32 want, long long& budget)
{
    while ((u32)(v >> 32) != want) {
        if (--budget < 0) break;            // bounded exit on protocol failure
        v = __hip_atomic_load(p, __ATOMIC_RELAXED, __HIP_MEMORY_SCOPE_AGENT);
    }
    union { unsigned u; float f; } c; c.u = (unsigned)v;
    return c.f;
}

__device__ __forceinline__ float poll_sleep(const ull* p, u32 want, long long& budget)
{
    ull v = __hip_atomic_load(p, __ATOMIC_RELAXED, __HIP_MEMORY_SCOPE_AGENT);
    while ((u32)(v >> 32) != want) {
        if (--budget < 0) break;
        __builtin_amdgcn_s_sleep(16);       // helpers have ~32us slack/step
        v = __hip_atomic_load(p, __ATOMIC_RELAXED, __HIP_MEMORY_SCOPE_AGENT);
    }
    union { unsigned u; float f; } c; c.u = (unsigned)v;
    return c.f;
}

__global__ __launch_bounds__(512, 2) void k_rec(const _Float16* __restrict__ PREh,
                                                const float* __restrict__ Wih,
                                                const float* __restrict__ Whh,
                                                ull* __restrict__ HT,
                                                ull* __restrict__ Z,
                                                const ull* __restrict__ RUN)
{
    // 144KB weight tail: row (pl*4+g) of 288 uint4; element offset
    // e + (e>>3) (one pad uint4 per 8) -> the 4 wave-aliased lanes
    // (e, e+8, e+16, e+24) land on distinct banks.
    __shared__ uint4 wlds[32 * 288];
    __shared__ __align__(16) _Float16 hs[2][256];   // h ping-pong (fp16 pairs)
    __shared__ __align__(16) float hb[256];         // helper h_{k-64} stage

    const int tid = threadIdx.x;
    const u32 salt = (u32)__hip_atomic_load(RUN, __ATOMIC_RELAXED,
                                            __HIP_MEMORY_SCOPE_AGENT) * 65536u;

    if (blockIdx.x == 0) {
        // ================= MASTER =================
        const int e = tid >> 1;       // element 0..255
        const int h = tid & 1;        // K-half: cols [128h, 128h+128)
        const int ebase = e + (e >> 3);   // swizzled LDS element offset

        // ---- stage weights: cols [0,96) -> 12 x u32x16 (192 VGPRs)
        u32x16 wv[12];
#pragma unroll
        for (int g = 0; g < 4; ++g) {
            const float* W = Whh + (size_t)(g*256 + e)*H + h*128;
#pragma unroll
            for (int c = 0; c < 48; ++c) {
                float2 f = *(const float2*)(W + 2*c);
                union { h2v hh; u32 u; } p;
                p.hh[0] = (_Float16)f.x; p.hh[1] = (_Float16)f.y;
                wv[g*3 + (c>>4)][c & 15] = p.u;
            }
        }
        // ---- LDS weights: cols [128h+96, 128h+128), 4 chunks of 4 dwords
#pragma unroll
        for (int g = 0; g < 4; ++g) {
            const float* W = Whh + (size_t)(g*256 + e)*H + h*128 + 96;
#pragma unroll
            for (int d4 = 0; d4 < 4; ++d4) {
                u32 u0, u1, u2, u3;
                {
                    float2 f; union { h2v hh; u32 uu; } p;
                    f = *(const float2*)(W + 8*d4 + 0); p.hh[0]=(_Float16)f.x; p.hh[1]=(_Float16)f.y; u0 = p.uu;
                    f = *(const float2*)(W + 8*d4 + 2); p.hh[0]=(_Float16)f.x; p.hh[1]=(_Float16)f.y; u1 = p.uu;
                    f = *(const float2*)(W + 8*d4 + 4); p.hh[0]=(_Float16)f.x; p.hh[1]=(_Float16)f.y; u2 = p.uu;
                    f = *(const float2*)(W + 8*d4 + 6); p.hh[0]=(_Float16)f.x; p.hh[1]=(_Float16)f.y; u3 = p.uu;
                }
                wlds[(size_t)((d4*2 + h)*4 + g)*288 + ebase] = make_uint4(u0, u1, u2, u3);
            }
        }
        if (tid < 128) ((u32*)hs[0])[tid] = 0u;    // h_{-1} = 0

        // z addresses: lane h owns gates {2h, 2h+1}
        const ull* zp0 = Z + (size_t)(2*h    )*256 + e;
        const ull* zp1 = Z + (size_t)(2*h + 1)*256 + e;
        ull zc0 = __hip_atomic_load(zp0, __ATOMIC_RELAXED, __HIP_MEMORY_SCOPE_AGENT);
        ull zc1 = __hip_atomic_load(zp1, __ATOMIC_RELAXED, __HIP_MEMORY_SCOPE_AGENT);

        float c_state = 0.f;
        long long budget = 2000000LL;
        __syncthreads();

        for (int k = 0; k < NSTEP; ++k) {
            // ---- prefetch z for k+1 (issued now, validated next iteration)
            const size_t sl_n = (size_t)((k+1) & (ZRING-1)) * GDIM;
            ull zn0 = __hip_atomic_load(zp0 + sl_n, __ATOMIC_RELAXED, __HIP_MEMORY_SCOPE_AGENT);
            ull zn1 = __hip_atomic_load(zp1 + sl_n, __ATOMIC_RELAXED, __HIP_MEMORY_SCOPE_AGENT);

            // ---- dot phase: 256 dot2/thread (broadcast LDS h reads)
            const uint4* hp = (const uint4*)((const char*)hs[k & 1] + h*256);
            float acc[4] = {0.f, 0.f, 0.f, 0.f};
            // cols [0,96): VGPR vector weights
#pragma unroll
            for (int q = 0; q < 12; ++q) {
                uint4 hv = hp[q];
#pragma unroll
                for (int g = 0; g < 4; ++g) {
                    acc[g] = dot2f(WVg(g, 4*q+0), hv.x, acc[g]);
                    acc[g] = dot2f(WVg(g, 4*q+1), hv.y, acc[g]);
                    acc[g] = dot2f(WVg(g, 4*q+2), hv.z, acc[g]);
                    acc[g] = dot2f(WVg(g, 4*q+3), hv.w, acc[g]);
                }
            }
            // cols [96,128): LDS weights (swizzled, <=2-way banks)
#pragma unroll
            for (int q = 12; q < 16; ++q) {
                uint4 hv = hp[q];
                const int pl = (q - 12)*2 + h;
#pragma unroll
                for (int g = 0; g < 4; ++g) {
                    uint4 wvv = wlds[(size_t)(pl*4 + g)*288 + ebase];
                    acc[g] = dot2f(wvv.x, hv.x, acc[g]);
                    acc[g] = dot2f(wvv.y, hv.y, acc[g]);
                    acc[g] = dot2f(wvv.z, hv.z, acc[g]);
                    acc[g] = dot2f(wvv.w, hv.w, acc[g]);
                }
            }

            // ---- fold z (static indices only)
            const size_t sl = (size_t)(k & (ZRING-1)) * GDIM;
            const u32 want = salt + (u32)k;
            const float z0 = z_wait(zc0, zp0 + sl, want, budget);
            const float z1 = z_wait(zc1, zp1 + sl, want, budget);
            if (h == 0) { acc[0] += z0; acc[1] += z1; }
            else        { acc[2] += z0; acc[3] += z1; }

            // ---- combine K-halves (pair lanes 2e,2e+1); identical in both lanes
            const float s0 = acc[0] + __shfl_xor(acc[0], 1);
            const float s1 = acc[1] + __shfl_xor(acc[1], 1);
            const float s2 = acc[2] + __shfl_xor(acc[2], 1);
            const float s3 = acc[3] + __shfl_xor(acc[3], 1);

            const float iv = sigm_fast(s0);
            const float fv = sigm_fast(s1);
            const float gv = tanh_fast(s2);
            const float ov = sigm_fast(s3);
            c_state = fv * c_state + iv * gv;
            const float hn = ov * tanh_fast(c_state);

            // ---- publish: LDS ping-pong (next step) + global tagged row
            //      (helpers + k_fc). ONE barrier per step.
            if (h == 0) {
                hs[(k + 1) & 1][e] = (_Float16)hn;
                union { float f; unsigned u; } cv; cv.f = hn;
                __hip_atomic_store(&HT[(ull)(k + 64) * H + e],
                                   ((ull)(salt + (u32)(k + 64)) << 32) | cv.u,
                                   __ATOMIC_RELAXED, __HIP_MEMORY_SCOPE_AGENT);
            }
            zc0 = zn0; zc1 = zn1;
            __syncthreads();
        }
    } else {
        // ================= HELPERS =================
        // WG wg handles k = wg, wg+64, ... : z_k = pre_k + Wo * h_{k-64}
        const int wg = blockIdx.x - 1;          // 0..63  (== ring slot, always)
        long long budget = 200000LL;            // sleep-polls; worst hang ~0.1s
        const int r0 = tid, r1 = tid + 512;
        const float* w0 = Wih + (size_t)r0 * W5 + 4*H;   // Wo row r0 (L2-resident)
        const float* w1 = Wih + (size_t)r1 * W5 + 4*H;

        for (int k = wg; k < NSTEP; k += NHELP) {
            // stage h_{k-64}: HT row k, CURRENT-run tag salt+k (k<64: k_init)
            if (tid < H) {
                hb[tid] = poll_sleep(&HT[(ull)k * H + tid], salt + (u32)k, budget);
            }
            __syncthreads();

            float a0 = (float)PREh[(size_t)k * GDIM + r0];
            float a1 = (float)PREh[(size_t)k * GDIM + r1];
#pragma unroll 4
            for (int j = 0; j < H; j += 4) {
                float4 hv = *(const float4*)(hb + j);
                float4 wa = *(const float4*)(w0 + j);
                float4 wb = *(const float4*)(w1 + j);
                a0 += wa.x*hv.x + wa.y*hv.y + wa.z*hv.z + wa.w*hv.w;
                a1 += wb.x*hv.x + wb.y*hv.y + wb.z*hv.z + wb.w*hv.w;
            }
            union { float f; unsigned u; } c0, c1; c0.f = a0; c1.f = a1;
            const ull tg = (ull)(salt + (u32)k) << 32;
            __hip_atomic_store(&Z[(size_t)(k & (ZRING-1))*GDIM + r0], tg | c0.u,
                               __ATOMIC_RELAXED, __HIP_MEMORY_SCOPE_AGENT);
            __hip_atomic_store(&Z[(size_t)(k & (ZRING-1))*GDIM + r1], tg | c1.u,
                               __ATOMIC_RELAXED, __HIP_MEMORY_SCOPE_AGENT);
            __syncthreads();   // protect hb before next iteration's overwrite
        }
    }
}

// ---------------------------------------------------------------------------
// K3: out[b][t][l] = b_fc[l] + sum_j h_k[j] * W_fc[l][j],  k = t*64+b
//     (unchanged; ignores tags — runs after k_rec completes)
// ---------------------------------------------------------------------------
__global__ __launch_bounds__(256) void k_fc(const ull* __restrict__ HT,
                                            const float* __restrict__ Wfc,
                                            const float* __restrict__ bfc,
                                            float* __restrict__ out)
{
    __shared__ float hl[8 * 256];
    __shared__ float wl[128 * 65];
    const int blk = blockIdx.x;     // 0..1023, k = blk*8 + kk
    const int tid = threadIdx.x;

#pragma unroll
    for (int kk = 0; kk < 8; kk++) {
        ull v = HT[((ull)(blk * 8 + kk + 64)) * H + tid];
        union { unsigned u; float f; } c; c.u = (unsigned)v;
        hl[kk * 256 + tid] = c.f;
    }

    const int l = tid & 127, grp = tid >> 7;
    float a0 = 0.f, a1 = 0.f, a2 = 0.f, a3 = 0.f;

    for (int c = 0; c < 4; c++) {
        __syncthreads();   // orders hl (c==0) and wl reuse (c>0)
        for (int m = 0; m < 32; m++) {
            const int idx = m * 256 + tid;
            const int lr = idx >> 6, jc = idx & 63;
            wl[lr * 65 + jc] = Wfc[(size_t)lr * H + c * 64 + jc];
        }
        __syncthreads();
#pragma unroll 4
        for (int jc = 0; jc < 64; jc++) {
            const float wv = wl[l * 65 + jc];
            const int hj = c * 64 + jc;
            a0 += hl[(grp * 4 + 0) * 256 + hj] * wv;
            a1 += hl[(grp * 4 + 1) * 256 + hj] * wv;
            a2 += hl[(grp * 4 + 2) * 256 + hj] * wv;
            a3 += hl[(grp * 4 + 3) * 256 + hj] * wv;
        }
    }

    const float bias = bfc[l];
    float accs[4] = {a0, a1, a2, a3};
#pragma unroll
    for (int r = 0; r < 4; r++) {
        const int k = blk * 8 + grp * 4 + r;
        const int t = k >> 6, b = k & 63;
        out[((size_t)b * LL + t) * LBL + l] = accs[r] + bias;
    }
}

// ---------------------------------------------------------------------------
extern "C" void kernel_launch(void* const* d_in, const int* in_sizes, int n_in,
                              void* d_out, int out_size, void* d_ws, size_t ws_size,
                              hipStream_t stream)
{
    const float* x   = (const float*)d_in[0];
    const float* hi  = (const float*)d_in[1];
    const float* Wih = (const float*)d_in[2];
    const float* Whh = (const float*)d_in[3];
    const float* bih = (const float*)d_in[4];
    const float* bhh = (const float*)d_in[5];
    const float* Wfc = (const float*)d_in[6];
    const float* bfc = (const float*)d_in[7];
    float* out = (float*)d_out;

    const size_t preh_b = (size_t)NSTEP * GDIM * sizeof(_Float16);   // 16 MB
    const size_t ht_b   = (size_t)NROW * H * sizeof(ull);            // 16.9 MB
    const size_t z_b    = (size_t)ZRING * GDIM * sizeof(ull);        // 512 KB

    _Float16* PREh = (_Float16*)d_ws;
    ull*      HT   = (ull*)((char*)d_ws + preh_b);
    ull*      Zr   = (ull*)((char*)d_ws + preh_b + ht_b);
    ull*      RUN  = (ull*)((char*)d_ws + preh_b + ht_b + z_b);

    const size_t need = preh_b + ht_b + z_b + sizeof(ull);
    if (ws_size < need) return;   // visible failure instead of OOB writes

    k_init<<<1, 256, 0, stream>>>(HT, RUN);
    k_pre<<<dim3(GDIM / 64, LL), 256, 0, stream>>>(x, hi, Wih, bih, bhh, PREh);
    k_rec<<<1 + NHELP, 512, 0, stream>>>(PREh, Wih, Whh, HT, Zr, RUN);
    k_fc<<<NSTEP / 8, 256, 0, stream>>>(HT, Wfc, bfc, out);
}